// Round 3
// baseline (231.952 us; speedup 1.0000x reference)
//
#include <hip/hip_runtime.h>

// CustomRNN: B=2048, T=512, I=1, H=64.
// Round-3 structure: MFMA across a 16-batch tile.
//   Block = 256 threads = 4 waves, owns 16 batches. Per step:
//     H_new[64h x 16b] = tanh( W_hh * H + xp ),  wave w computes M-rows
//     [16w,16w+16) via mfma_f32_16x16x32_f16 (M=h_out, N=batch, K=h_in).
//   h carried as fp16 hi/lo pair (exact to ~2^-21); W as fp16 hi/lo; 3 mfma
//   products (hi*hi, lo*hi, hi*lo; lo*lo negligible) accumulate in fp32.
//   tanh in fp32 (exp2+rcp). LDS round-trip per step: 4 ds_read_b128 (B-frags)
//   + 1 ds_read_b32 (x) + 2 ds_write_b64 per wave  (vs 17 DS/batch-step in the
//   round-2 broadcast scheme -> ~38x less DS traffic).
// Layouts (verified claims from the guide):
//   A[m=lane&15][k=quad*8+j], B[k=quad*8+j][n=lane&15],
//   D col=lane&15 (=batch), row=quad*4+reg (=h_out within tile).
// H buffer: [parity][hi/lo][batch][k] with k-stride 72 fp16 (144 B: 16B-aligned
// rows, bank-uniform for both b128 reads and b64 writes).

typedef _Float16 v8h __attribute__((ext_vector_type(8)));
typedef _Float16 v4h __attribute__((ext_vector_type(4)));
typedef float    v4f __attribute__((ext_vector_type(4)));

#define LDK 72   // padded k-stride in halves

__global__ __launch_bounds__(256) void rnn_mfma(
    const float* __restrict__ x,      // [B, T]
    const float* __restrict__ W_ih,   // [64, 1]
    const float* __restrict__ W_hh,   // [64, 64]
    const float* __restrict__ b_ih,   // [64]
    const float* __restrict__ b_hh,   // [64]
    const float* __restrict__ fc_w,   // [1, 64]
    const float* __restrict__ fc_b,   // [1]
    float* __restrict__ out,          // [B, 1]
    int B, int T)
{
    const int lane = threadIdx.x & 63;
    const int wv   = threadIdx.x >> 6;   // M-tile: h rows [16wv, 16wv+16)
    const int q    = lane >> 4;          // quad
    const int col  = lane & 15;          // batch col (B,D) / A-row (A)
    const int batch0 = blockIdx.x * 16;

    __shared__ __align__(16) _Float16 H[2][2][16][LDK]; // [parity][hi|lo][b][k]
    __shared__ __align__(16) float xs[64][16];

    // zero both parities (t=0 reads parity 0; parity 1 written before read)
    for (int i = threadIdx.x; i < 2 * 2 * 16 * LDK; i += 256)
        (&H[0][0][0][0])[i] = (_Float16)0.0f;

    // A fragments: lane holds A[m=col][k=q*8+j] of W rows 16wv+col, hi/lo fp16.
    v8h Ahi[2], Alo[2];
    {
        const float* wrow = W_hh + (size_t)(16 * wv + col) * 64;
#pragma unroll
        for (int kt = 0; kt < 2; ++kt)
#pragma unroll
            for (int j = 0; j < 8; ++j) {
                const float w = wrow[kt * 32 + q * 8 + j];
                const _Float16 hi = (_Float16)w;
                Ahi[kt][j] = hi;
                Alo[kt][j] = (_Float16)(w - (float)hi);
            }
    }
    // per-lane epilogue constants for its 4 D rows r = 16wv + 4q + i
    float bias[4], wih[4];
#pragma unroll
    for (int i = 0; i < 4; ++i) {
        const int r = 16 * wv + 4 * q + i;
        bias[i] = b_ih[r] + b_hh[r];
        wih[i]  = W_ih[r];
    }
    __syncthreads();

    // one RNN step at parity p (reads H[p], writes H[1-p], barrier at end)
    auto step = [&](int p, int tt) {
        const v8h bh0 = *(const v8h*)&H[p][0][col][q * 8];
        const v8h bh1 = *(const v8h*)&H[p][0][col][32 + q * 8];
        const v8h bl0 = *(const v8h*)&H[p][1][col][q * 8];
        const v8h bl1 = *(const v8h*)&H[p][1][col][32 + q * 8];
        const v4f z = {0.f, 0.f, 0.f, 0.f};
        v4f acc0 = __builtin_amdgcn_mfma_f32_16x16x32_f16(Ahi[0], bh0, z, 0, 0, 0);
        acc0     = __builtin_amdgcn_mfma_f32_16x16x32_f16(Ahi[1], bh1, acc0, 0, 0, 0);
        v4f acc1 = __builtin_amdgcn_mfma_f32_16x16x32_f16(Alo[0], bh0, z, 0, 0, 0);
        acc1     = __builtin_amdgcn_mfma_f32_16x16x32_f16(Alo[1], bh1, acc1, 0, 0, 0);
        v4f acc2 = __builtin_amdgcn_mfma_f32_16x16x32_f16(Ahi[0], bl0, z, 0, 0, 0);
        acc2     = __builtin_amdgcn_mfma_f32_16x16x32_f16(Ahi[1], bl1, acc2, 0, 0, 0);
        const float xv = xs[tt][col];

        v4h hh, hl;
#pragma unroll
        for (int i = 0; i < 4; ++i) {
            const float a  = ((acc0[i] + acc1[i]) + acc2[i])
                           + __builtin_fmaf(xv, wih[i], bias[i]);
            const float ax = __builtin_fabsf(a);
            const float e  = __builtin_amdgcn_exp2f(ax * -2.885390082f); // exp(-2ax)
            const float th = (1.0f - e) * __builtin_amdgcn_rcpf(1.0f + e);
            const float hn = __builtin_copysignf(th, a);
            const _Float16 hi = (_Float16)hn;
            hh[i] = hi;
            hl[i] = (_Float16)(hn - (float)hi);
        }
        const int kb = 16 * wv + 4 * q;   // 4 consecutive k, 8B-aligned
        *(v4h*)&H[1 - p][0][col][kb] = hh;
        *(v4h*)&H[1 - p][1][col][kb] = hl;
        __syncthreads();   // writers of H[1-p] done before step t+1 reads/writes
    };

    for (int t0 = 0; t0 < T; t0 += 64) {
        // stage 16 batches x 64 timesteps of x (coalesced: consecutive tid -> consecutive t)
        {
            const int tl = threadIdx.x & 63;
            const int bq = threadIdx.x >> 6;
#pragma unroll
            for (int j = 0; j < 4; ++j) {
                const int b  = bq + 4 * j;
                const int gb = batch0 + b;
                xs[tl][b] = (gb < B) ? x[(size_t)gb * T + t0 + tl] : 0.0f;
            }
        }
        __syncthreads();
        for (int tt = 0; tt < 64; tt += 2) {   // pin parity at compile time
            step((t0 & 1) ^ 0, tt);
            step((t0 & 1) ^ 1, tt + 1);
        }
    }

    // epilogue: final h lives in parity (T & 1); out[b] = fc_w . h_b + fc_b
    const int pf = T & 1;
    const float fw = fc_w[lane];
#pragma unroll
    for (int j = 0; j < 4; ++j) {
        const int b = wv * 4 + j;
        float h = (float)H[pf][0][b][lane] + (float)H[pf][1][b][lane];
        float v = h * fw;
#pragma unroll
        for (int off = 32; off > 0; off >>= 1)
            v += __shfl_xor(v, off, 64);
        if (lane == 0 && batch0 + b < B) out[batch0 + b] = v + fc_b[0];
    }
}

extern "C" void kernel_launch(void* const* d_in, const int* in_sizes, int n_in,
                              void* d_out, int out_size, void* d_ws, size_t ws_size,
                              hipStream_t stream) {
    const float* x    = (const float*)d_in[0];
    const float* W_ih = (const float*)d_in[1];
    const float* W_hh = (const float*)d_in[2];
    const float* b_ih = (const float*)d_in[3];
    const float* b_hh = (const float*)d_in[4];
    const float* fc_w = (const float*)d_in[5];
    const float* fc_b = (const float*)d_in[6];
    float* out = (float*)d_out;

    const int B = out_size;          // output is [B, 1]
    const int T = in_sizes[0] / B;   // I == 1

    const int blocks = (B + 15) / 16;
    rnn_mfma<<<blocks, 256, 0, stream>>>(x, W_ih, W_hh, b_ih, b_hh,
                                         fc_w, fc_b, out, B, T);
}

// Round 5
// 214.155 us; speedup vs baseline: 1.0831x; 1.0831x over previous
//
#include <hip/hip_runtime.h>

// CustomRNN: B=2048, T=512, I=1, H=64.
// MFMA 16-batch tile, 4 waves/block (wave w owns h-rows [16w,16w+16)).
// Per step (latency-bound, one barrier per step):
//   read B-frags (h hi/lo, XOR-swizzled conflict-free) -> 6 mfma (hi*hi,
//   lo*hi, hi*lo) -> v4f combine + exp2/rcp tanh -> pkrtz hi/lo pack ->
//   2 ds_write_b64 (swizzled) -> barrier.
// Round-3 lesson: 72-half pad gave 6.78M bank conflicts (~100 cyc/step) and
// the scalar epilogue another ~170; both attacked here. All x staged to LDS
// once at entry (no staging inside the 512-step chain).
// Layouts (verified round 3, absmax 0.0): A[m=lane&15][k=q*8+j],
// B[k=q*8+j][n=lane&15], D col=lane&15, row=q*4+reg.
// Swizzle: element (plane, b, k) at plane*2048 + b*128 + ((k>>3 ^ (b&7))*8
// + (k&7))*2 bytes. 8-lane phase groups hit 32 distinct banks for both the
// b128 reads and b64 writes.
// Round-4 fix: __builtin_amdgcn_cvt_pkrtz returns __fp16 ext-vector, not
// _Float16 ext-vector -> receive into __fp16 vec and element-cast.

typedef _Float16 v8h __attribute__((ext_vector_type(8)));
typedef _Float16 v4h __attribute__((ext_vector_type(4)));
typedef __fp16   v2hp __attribute__((ext_vector_type(2)));  // pkrtz result type
typedef float    v4f __attribute__((ext_vector_type(4)));

#define TMAX 512

__global__ __launch_bounds__(256) void rnn_mfma(
    const float* __restrict__ x,      // [B, T]
    const float* __restrict__ W_ih,   // [64, 1]
    const float* __restrict__ W_hh,   // [64, 64]
    const float* __restrict__ b_ih,   // [64]
    const float* __restrict__ b_hh,   // [64]
    const float* __restrict__ fc_w,   // [1, 64]
    const float* __restrict__ fc_b,   // [1]
    float* __restrict__ out,          // [B, 1]
    int B, int T)
{
    const int tid  = threadIdx.x;
    const int lane = tid & 63;
    const int wv   = tid >> 6;   // M-tile: h rows [16wv, 16wv+16)
    const int q    = lane >> 4;  // quad
    const int col  = lane & 15;  // batch col
    const int batch0 = blockIdx.x * 16;

    // H: 2 parities x 2 planes (hi,lo) x 16 batches x 64 halves (swizzled)
    __shared__ __align__(16) _Float16 Hbuf[2 * 2 * 16 * 64];
    __shared__ __align__(16) float xs[TMAX][17];   // [t][batch], +1 pad

    // ---- one-time staging ----
    for (int i = tid; i < 2048; i += 256) ((int*)Hbuf)[i] = 0;  // zero H

    const int Tc = (T < TMAX) ? T : TMAX;
    if ((T & 3) == 0) {
        for (int base = tid * 4; base < 16 * Tc; base += 1024) {
            const int b  = base / Tc;
            const int t  = base - b * Tc;
            const int gb = batch0 + b;
            float4 v = make_float4(0.f, 0.f, 0.f, 0.f);
            if (gb < B) v = *(const float4*)(x + (size_t)gb * T + t);
            xs[t + 0][b] = v.x; xs[t + 1][b] = v.y;
            xs[t + 2][b] = v.z; xs[t + 3][b] = v.w;
        }
    } else {
        for (int base = tid; base < 16 * Tc; base += 256) {
            const int b  = base / Tc;
            const int t  = base - b * Tc;
            const int gb = batch0 + b;
            xs[t][b] = (gb < B) ? x[(size_t)gb * T + t] : 0.f;
        }
    }

    // A fragments: lane holds A[m=col][k=q*8+j] of W row 16wv+col, hi/lo fp16.
    v8h Ahi[2], Alo[2];
    {
        const float* wrow = W_hh + (size_t)(16 * wv + col) * 64;
#pragma unroll
        for (int kt = 0; kt < 2; ++kt)
#pragma unroll
            for (int j = 0; j < 8; ++j) {
                const float w = wrow[kt * 32 + q * 8 + j];
                const _Float16 hi = (_Float16)w;
                Ahi[kt][j] = hi;
                Alo[kt][j] = (_Float16)(w - (float)hi);
            }
    }
    float bias[4], wih[4];
#pragma unroll
    for (int i = 0; i < 4; ++i) {
        const int r = 16 * wv + 4 * q + i;
        bias[i] = b_ih[r] + b_hh[r];
        wih[i]  = W_ih[r];
    }

    // ---- precomputed swizzled LDS byte offsets (loop-invariant) ----
    const int c7 = col & 7;
    auto hoff = [&](int pp, int hl, int kb) {
        return ((pp * 2 + hl) * 16 + col) * 128 + ((kb ^ c7) << 4);
    };
    int ro[2][4], wo[2][2];
#pragma unroll
    for (int pp = 0; pp < 2; ++pp) {
        ro[pp][0] = hoff(pp, 0, q);       // hi, k = 8q..8q+7
        ro[pp][1] = hoff(pp, 0, q + 4);   // hi, k = 32+8q..
        ro[pp][2] = hoff(pp, 1, q);       // lo
        ro[pp][3] = hoff(pp, 1, q + 4);
        const int kb = 2 * wv + (q >> 1); // write: k = 16wv+4q (4 halves)
        wo[pp][0] = hoff(pp, 0, kb) + 8 * (q & 1);
        wo[pp][1] = hoff(pp, 1, kb) + 8 * (q & 1);
    }
    char* Hb = (char*)Hbuf;

    __syncthreads();   // staging + zero-init visible

    // one RNN step: reads H[p], writes H[1-p], one barrier
    auto step = [&](int p, int t) {
        const v8h bh0 = *(const v8h*)(Hb + ro[p][0]);
        const v8h bh1 = *(const v8h*)(Hb + ro[p][1]);
        const v8h bl0 = *(const v8h*)(Hb + ro[p][2]);
        const v8h bl1 = *(const v8h*)(Hb + ro[p][3]);
        const float xv = xs[t][col];

        const v4f z = {0.f, 0.f, 0.f, 0.f};
        v4f acc0 = __builtin_amdgcn_mfma_f32_16x16x32_f16(Ahi[0], bh0, z, 0, 0, 0);
        acc0     = __builtin_amdgcn_mfma_f32_16x16x32_f16(Ahi[1], bh1, acc0, 0, 0, 0);
        v4f acc1 = __builtin_amdgcn_mfma_f32_16x16x32_f16(Alo[0], bh0, z, 0, 0, 0);
        acc1     = __builtin_amdgcn_mfma_f32_16x16x32_f16(Alo[1], bh1, acc1, 0, 0, 0);
        v4f acc2 = __builtin_amdgcn_mfma_f32_16x16x32_f16(Ahi[0], bl0, z, 0, 0, 0);
        acc2     = __builtin_amdgcn_mfma_f32_16x16x32_f16(Ahi[1], bl1, acc2, 0, 0, 0);

        v4f cxp;
#pragma unroll
        for (int i = 0; i < 4; ++i) cxp[i] = __builtin_fmaf(xv, wih[i], bias[i]);
        const v4f s = (acc0 + acc1) + (acc2 + cxp);   // pk_add_f32

        // tanh(a) = 1 - 2/(exp2(a*2/ln2) + 1)   (handles +/-inf saturation)
        float th[4];
#pragma unroll
        for (int i = 0; i < 4; ++i) {
            const float e2 = __builtin_amdgcn_exp2f(s[i] * 2.885390081777927f);
            th[i] = __builtin_fmaf(-2.0f, __builtin_amdgcn_rcpf(1.0f + e2), 1.0f);
        }
        const v2hp hh01 = __builtin_amdgcn_cvt_pkrtz(th[0], th[1]);
        const v2hp hh23 = __builtin_amdgcn_cvt_pkrtz(th[2], th[3]);
        const v2hp hl01 = __builtin_amdgcn_cvt_pkrtz(th[0] - (float)hh01[0],
                                                     th[1] - (float)hh01[1]);
        const v2hp hl23 = __builtin_amdgcn_cvt_pkrtz(th[2] - (float)hh23[0],
                                                     th[3] - (float)hh23[1]);
        const v4h hhv = { (_Float16)(float)hh01[0], (_Float16)(float)hh01[1],
                          (_Float16)(float)hh23[0], (_Float16)(float)hh23[1] };
        const v4h hlv = { (_Float16)(float)hl01[0], (_Float16)(float)hl01[1],
                          (_Float16)(float)hl23[0], (_Float16)(float)hl23[1] };
        *(v4h*)(Hb + wo[1 - p][0]) = hhv;
        *(v4h*)(Hb + wo[1 - p][1]) = hlv;
        __syncthreads();
    };

    for (int t = 0; t + 1 < Tc; t += 2) { step(0, t); step(1, t + 1); }
    if (Tc & 1) step(0, Tc - 1);

    // ---- epilogue: out[b] = fc_w . h_b + fc_b, final h in parity (T&1) ----
    const int pf = Tc & 1;
    const float fw = fc_w[lane];
#pragma unroll
    for (int j = 0; j < 4; ++j) {
        const int b   = wv * 4 + j;
        const int off = (((lane >> 3) ^ (b & 7)) << 3) | (lane & 7);
        const float h = (float)Hbuf[((pf * 2 + 0) * 16 + b) * 64 + off]
                      + (float)Hbuf[((pf * 2 + 1) * 16 + b) * 64 + off];
        float v = h * fw;
#pragma unroll
        for (int o = 32; o > 0; o >>= 1) v += __shfl_xor(v, o, 64);
        if (lane == 0 && batch0 + b < B) out[batch0 + b] = v + fc_b[0];
    }
}

extern "C" void kernel_launch(void* const* d_in, const int* in_sizes, int n_in,
                              void* d_out, int out_size, void* d_ws, size_t ws_size,
                              hipStream_t stream) {
    const float* x    = (const float*)d_in[0];
    const float* W_ih = (const float*)d_in[1];
    const float* W_hh = (const float*)d_in[2];
    const float* b_ih = (const float*)d_in[3];
    const float* b_hh = (const float*)d_in[4];
    const float* fc_w = (const float*)d_in[5];
    const float* fc_b = (const float*)d_in[6];
    float* out = (float*)d_out;

    const int B = out_size;          // output is [B, 1]
    const int T = in_sizes[0] / B;   // I == 1

    const int blocks = (B + 15) / 16;
    rnn_mfma<<<blocks, 256, 0, stream>>>(x, W_ih, W_hh, b_ih, b_hh,
                                         fc_w, fc_b, out, B, T);
}